// Round 21
// baseline (58.055 us; speedup 1.0000x reference)
//
#include <hip/hip_runtime.h>

#define DZ 512
#define DT 66048
#define NT 4128  // 16-col tiles
#define SV_JITTER 1e-4f

typedef __attribute__((ext_vector_type(8))) short bf8;
typedef __attribute__((ext_vector_type(4))) short bf4;
typedef __attribute__((ext_vector_type(4))) float f4;

// Raw barrier: waits ONLY lgkmcnt (LDS visibility) -- in-flight global
// loads/stores survive the barrier (R18-proven safe).
#define BAR()                                                   \
  do {                                                          \
    __builtin_amdgcn_sched_barrier(0);                          \
    asm volatile("s_waitcnt lgkmcnt(0)" ::: "memory");          \
    __builtin_amdgcn_s_barrier();                               \
    __builtin_amdgcn_sched_barrier(0);                          \
  } while (0)

__device__ __forceinline__ short f2bf(float f) {
  unsigned u = __builtin_bit_cast(unsigned, f);
  return (short)((u + 0x7FFFu + ((u >> 16) & 1u)) >> 16);
}

__device__ __forceinline__ bf8 cvt8(f4 a, f4 b) {
  bf8 r = { f2bf(a[0]), f2bf(a[1]), f2bf(a[2]), f2bf(a[3]),
            f2bf(b[0]), f2bf(b[1]), f2bf(b[2]), f2bf(b[3]) };
  return r;
}

// tril/jitter cvt: element t has k-index kbase+t
__device__ __forceinline__ bf8 cvt8_tril(f4 x, f4 y, int kbase, int diag) {
  bf8 r;
  #pragma unroll
  for (int t = 0; t < 8; ++t) {
    const int k = kbase + t;
    const float vt = (t < 4) ? x[t] : y[t - 4];
    const float val = (k < diag) ? vt : ((k == diag) ? vt + SV_JITTER : 0.f);
    r[t] = f2bf(val);
  }
  return r;
}

// TWO BLOCKS PER CU: 512 blocks x 256 threads (4 waves). Block (half=b>>8)
// owns 64 samples; bcol=b&255 walks 16-col tiles T = bcol+256r. LDS = 80KB
// exactly (64KB Afrag + 16KB Bpan) -> 2 co-resident blocks/CU whose phases
// (HBM stream wait vs LDS/MFMA) overlap ACROSS blocks -- the mechanism the
// 1-block/CU designs (R5..R19, all ~51us = phase SUM) could not create.
//   Afrag 64KB: half's eps_z bf16, frag layout region r=kk*4+mi, slot=lane.
//   Bpan  16KB: tile's B panel [16 rows][512 k] bf16, R13 XOR swizzle,
//               tril/jitter baked at stage time.
// Per round: contiguous 32KB slab (16 rows x 2KB) read as 8 x 1KB-per-wave-
// instr sequential bursts -> 32 VGPR -> LDS (load-early/write-late).
// K-loop: 1 A-read + 1 B-read + 1 MFMA per kk, pure LDS.
// acc layout per mfma_f32_16x16x32_bf16: col=lane&15, row=4*(lane>>4)+reg.
__global__ __launch_bounds__(256, 2)
void sv_kernel(const float* __restrict__ mv, const float* __restrict__ Lz,
               const float* __restrict__ Ly, const float* __restrict__ Lyz,
               const float* __restrict__ eps, float* __restrict__ out) {
  __shared__ short Afrag[64 * 512];  // 64 KB (64 regions x 512 shorts)
  __shared__ short Bpan[16 * 512];   // 16 KB

  const int tid = threadIdx.x;   // 0..255
  const int lane = tid & 63;
  const int wv = tid >> 6;       // 0..3 = sample subgroup (16 rows)
  const int lcol = lane & 15;
  const int q = lane >> 4;
  const int b = blockIdx.x;      // 0..511
  const int half = b >> 8;       // sample half (rows 64*half..+63)
  const int bcol = b & 255;
  const int srow0 = 64 * half;

  f4 sv[8];  // staged panel floats (32 VGPR), static indices only
  auto stage_load = [&](int T) {
    const float* Ls = (T < 32) ? (Lz + (size_t)(16 * T) * DZ)
                               : (Lyz + (size_t)(16 * T) * DZ - (size_t)DZ * DZ);
    #pragma unroll
    for (int i = 0; i < 8; ++i)
      sv[i] = *(const f4*)(Ls + (size_t)4 * (i * 256 + tid));
  };
  // float4 f: panel row ro=f>>7 (16 rows), c4=f&127 -> 8B bf16 at
  // ro*1024 + ((c4>>1 ^ (ro&7))<<4) + (c4&1)*8  (R13-proven swizzle).
  auto stage_write = [&](int T) {
    #pragma unroll
    for (int i = 0; i < 8; ++i) {
      const int f = i * 256 + tid;
      const int ro = f >> 7;
      const int c4 = f & 127;
      bf4 w;
      if (T < 32) {  // z tile: tril + jitter baked in at stage time
        const int gcol = 16 * T + ro;
        #pragma unroll
        for (int t = 0; t < 4; ++t) {
          const int k = 4 * c4 + t;
          const float val =
              (k < gcol) ? sv[i][t] : ((k == gcol) ? sv[i][t] + SV_JITTER : 0.f);
          w[t] = f2bf(val);
        }
      } else {
        #pragma unroll
        for (int t = 0; t < 4; ++t) w[t] = f2bf(sv[i][t]);
      }
      const int off = (ro << 10) + ((((c4 >> 1) ^ (ro & 7))) << 4) + ((c4 & 1) << 3);
      *(bf4*)((char*)Bpan + off) = w;
    }
  };
  // B-frag read: row R=lcol, swizzled 16B slot 4kk+q
  auto readB = [&](int kk) -> bf8 {
    const int off = (lcol << 10) + (((4 * kk + q) ^ (lcol & 7)) << 4);
    return *(const bf8*)((const char*)Bpan + off);
  };

  // ---- prologue: issue tile(bcol) panel stream (oldest), stage Afrag once
  stage_load(bcol);
  {  // half's eps_z -> Afrag: region r = kk*4+mi, slot=lane
    const int slot = lane;
    #pragma unroll 4
    for (int i = 0; i < 16; ++i) {
      const int r = wv * 16 + i;  // wave wv stages kk in [4wv, 4wv+4)
      const int mi = r & 3, kk = r >> 2;
      const float* p = eps + (size_t)(srow0 + 16 * mi + (slot & 15)) * DT +
                       kk * 32 + (slot >> 4) * 8;
      const f4 x = *(const f4*)p;
      const f4 y = *(const f4*)(p + 4);
      *(bf8*)&Afrag[r * 512 + slot * 8] = cvt8(x, y);
    }
  }
  stage_write(bcol);
  BAR();

  #pragma unroll 1
  for (int r = 0; r < 17; ++r) {
    const int T = bcol + 256 * r;
    if (T >= NT) break;
    const bool isz = (T < 32);
    const int Tn = T + 256;
    const bool have_next = (Tn < NT);

    if (have_next) stage_load(Tn);  // sequential burst, oldest vmem of round

    // diag-step loads (y tiles): land under compute
    f4 dax, day, dbx, dby;
    int dI = 0;
    if (!isz) {
      const int nb = (T - 32) >> 1;  // 32x32 Ly block
      dI = (T & 1) * 16;             // tile's base row within the block
      const float* pa =
          eps + (size_t)(srow0 + 16 * wv + lcol) * DT + DZ + (size_t)nb * 32 + 8 * q;
      dax = *(const f4*)pa; day = *(const f4*)(pa + 4);
      const float* pb = Ly + ((size_t)nb * 32 + dI + lcol) * 32 + 8 * q;
      dbx = *(const f4*)pb; dby = *(const f4*)(pb + 4);
    }

    // ---- compute: pure LDS + MFMA (one 16x16 acc per wave)
    f4 acc = f4{0.f, 0.f, 0.f, 0.f};
    #pragma unroll
    for (int kk = 0; kk < 16; ++kk) {
      const bf8 af = *(const bf8*)&Afrag[(kk * 4 + wv) * 512 + lane * 8];
      const bf8 bf = readB(kk);
      acc = __builtin_amdgcn_mfma_f32_16x16x32_bf16(af, bf, acc, 0, 0, 0);
    }
    if (!isz) {  // block-diag einsum step
      const bf8 afd = cvt8(dax, day);
      const bf8 dbf = cvt8_tril(dbx, dby, 8 * q, dI + lcol);
      acc = __builtin_amdgcn_mfma_f32_16x16x32_bf16(afd, dbf, acc, 0, 0, 0);
    }

    // ---- epilogue: 16 consecutive cols per sample row (64B runs)
    {
      const int c0 = 16 * T + lcol;
      const float m0 = mv[c0];
      #pragma unroll
      for (int rr = 0; rr < 4; ++rr) {
        out[(size_t)(srow0 + 16 * wv + 4 * q + rr) * DT + c0] = acc[rr] + m0;
      }
    }

    BAR();                           // readers done (lgkm only; vmem in flight)
    if (have_next) stage_write(Tn);  // compiler inserts precise vmcnt per sv use
    BAR();                           // new panel visible
  }
}

extern "C" void kernel_launch(void* const* d_in, const int* in_sizes, int n_in,
                              void* d_out, int out_size, void* d_ws, size_t ws_size,
                              hipStream_t stream) {
  const float* m   = (const float*)d_in[0];
  const float* Lz  = (const float*)d_in[1];
  const float* Ly  = (const float*)d_in[2];
  const float* Lyz = (const float*)d_in[3];
  const float* eps = (const float*)d_in[4];
  float* out = (float*)d_out;
  sv_kernel<<<dim3(512), dim3(256), 0, stream>>>(m, Lz, Ly, Lyz, eps, out);
}